// Round 4
// baseline (1659.760 us; speedup 1.0000x reference)
//
#include <hip/hip_runtime.h>
#include <math.h>

// MosfetFNO on MI355X — MFMA bf16 hi/lo (3-product emu), activations stored
// pre-silu'd + pre-split.  B=128, T=4096, Tp=4506, TPAD=4608.
// ws (185,139,200 B, same as prev round):
//   hx,lx u16 [128][64][4608]   2×75,497,472 B   (silu'd activations, split)
//   xfp   f32 [6][8192][128]      25,165,824 B
//   coefh/l u16 [128][64][128]   2×2,097,152 B   (latb f32 aliases coefh,
//                                                 lw2T h/l aliases coefl)
//   fwdFh/l u16 [4608][128]      2×1,179,648 B
//   invFh/l u16 [128][4608]      2×1,179,648 B
//   skwh/l  u16 [4][64][64]      2×32,768 B
#define B_     128
#define T_     4096
#define TP_    4506
#define TPAD_  4608
#define KSPLIT 6
#define NL_    4

typedef __attribute__((ext_vector_type(8))) short bf16x8;
typedef __attribute__((ext_vector_type(4))) float f32x4;
typedef unsigned short u16;

__device__ __forceinline__ float silu_f(float x){
  return x / (1.0f + expf(-x));
}
__device__ __forceinline__ float gelu_f(float x){
  float u = x + 0.044715f*x*x*x;
  return 0.5f*x*(1.0f + tanhf(0.7978845608028654f*u));
}
__device__ __forceinline__ u16 bf16_rne(float f){
  unsigned u = __float_as_uint(f);
  unsigned r = u + 0x7FFFu + ((u >> 16) & 1u);
  return (u16)(r >> 16);
}
__device__ __forceinline__ void bf16_split(float f, u16& h, u16& l){
  h = bf16_rne(f);
  float fh = __uint_as_float(((unsigned)h) << 16);
  l = bf16_rne(f - fh);
}
__device__ __forceinline__ void silu_split(float v, u16& h, u16& l){
  float s = v / (1.0f + __expf(-v));
  bf16_split(s, h, l);
}
__device__ __forceinline__ float bf2f(u16 h){
  return __uint_as_float(((unsigned)h) << 16);
}
__device__ __forceinline__ f32x4 mfma16(bf16x8 a, bf16x8 b, f32x4 c){
  return __builtin_amdgcn_mfma_f32_16x16x32_bf16(a, b, c, 0, 0, 0);
}

#define FMA8x8(ACC, A0, A1, B0, B1) do {                                   \
  float av_[8] = {A0.x,A0.y,A0.z,A0.w,A1.x,A1.y,A1.z,A1.w};                \
  float bv_[8] = {B0.x,B0.y,B0.z,B0.w,B1.x,B1.y,B1.z,B1.w};                \
  _Pragma("unroll")                                                        \
  for(int i_=0;i_<8;i_++){                                                 \
    _Pragma("unroll")                                                      \
    for(int j_=0;j_<8;j_++) ACC[i_][j_] += av_[i_]*bv_[j_];                \
  }                                                                        \
} while(0)

// ---------------------------------------------------------------- tables
__global__ __launch_bounds__(256) void k_tables(u16* __restrict__ fwdFh,
    u16* __restrict__ fwdFl, u16* __restrict__ invFh, u16* __restrict__ invFl){
  int idx = blockIdx.x*256 + threadIdx.x;
  if(idx >= TPAD_*64) return;
  int t = idx >> 6, m = idx & 63;
  float c = 0.f, s = 0.f;
  if(t < TP_){
    int r = (int)(((long long)m * (long long)t) % TP_);
    double ang = 6.283185307179586476925287 * (double)r / (double)TP_;
    c = (float)cos(ang);
    s = -(float)sin(ang);
  }
  u16 ch, cl, sh, sl;
  bf16_split(c, ch, cl);
  bf16_split(s, sh, sl);
  fwdFh[t*128 + m] = ch;      fwdFl[t*128 + m] = cl;
  fwdFh[t*128 + 64 + m] = sh; fwdFl[t*128 + 64 + m] = sl;
  invFh[(long)m*TPAD_ + t] = ch;      invFl[(long)m*TPAD_ + t] = cl;
  invFh[(long)(64+m)*TPAD_ + t] = sh; invFl[(long)(64+m)*TPAD_ + t] = sl;
}

// skip weights + lw2^T -> bf16 hi/lo
__global__ __launch_bounds__(256) void k_prep(const float* __restrict__ skw,
    u16* __restrict__ skwh, u16* __restrict__ skwl,
    const float* __restrict__ lw2, u16* __restrict__ lw2Th,
    u16* __restrict__ lw2Tl){
  int i = blockIdx.x*256 + threadIdx.x;
  if(i < NL_*64*64){
    u16 h, l; bf16_split(skw[i], h, l);
    skwh[i] = h; skwl[i] = l;
  } else if(i < NL_*64*64 + 64*128){
    int j = i - NL_*64*64;
    int w = j >> 7, d = j & 127;
    u16 h, l; bf16_split(lw2[d*64 + w], h, l);
    lw2Th[j] = h; lw2Tl[j] = l;
  }
}

// ---------------------------------------------------------------- embed
__global__ __launch_bounds__(128) void k_embed(
    const float* __restrict__ pp,
    const float* __restrict__ ew1, const float* __restrict__ eb1,
    const float* __restrict__ ew2, const float* __restrict__ eb2,
    const float* __restrict__ ew3, const float* __restrict__ eb3,
    const float* __restrict__ lw1, const float* __restrict__ lb1,
    float* __restrict__ latb)
{
  int b = blockIdx.x, tid = threadIdx.x;
  __shared__ float p[64], h1[128], h2[128], e[32];
  if(tid < 64) p[tid] = pp[b*64 + tid];
  __syncthreads();
  {
    float z = eb1[tid];
    for(int j=0;j<64;j++) z += p[j]*ew1[j*128 + tid];
    h1[tid] = gelu_f(z);
  }
  __syncthreads();
  {
    float z = eb2[tid];
    for(int j=0;j<128;j++) z += h1[j]*ew2[j*128 + tid];
    h2[tid] = gelu_f(z);
  }
  __syncthreads();
  if(tid < 32){
    float z = eb3[tid];
    for(int j=0;j<128;j++) z += h2[j]*ew3[j*32 + tid];
    e[tid] = tanhf(z);
  }
  __syncthreads();
  {
    float v = lb1[tid];
    for(int c=0;c<32;c++) v += e[c]*lw1[(4+c)*128 + tid];
    latb[b*128 + tid] = v;
  }
}

// ---------------------------------------------------------------- lift (MFMA)
// hx/lx[b][w][t] = split( silu( lw2T . silu(z1) + lb2 ) ), zeros t>=T
__global__ __launch_bounds__(256) void k_lift(
    const float* __restrict__ vterm, const float* __restrict__ latb,
    const float* __restrict__ lw1,  const u16* __restrict__ lw2Th,
    const u16* __restrict__ lw2Tl, const float* __restrict__ lb2,
    u16* __restrict__ hx, u16* __restrict__ lx)
{
  int tt = blockIdx.x, b = blockIdx.y, tid = threadIdx.x;
  int t0 = tt*128;
  if(t0 >= T_){
    int r = tid >> 2, t00 = (tid & 3)*32;
    bf16x8 z8 = (bf16x8){0,0,0,0,0,0,0,0};
    long base = ((long)b*64 + r)*TPAD_ + t0 + t00;
    #pragma unroll
    for(int q=0;q<4;q++){
      *(bf16x8*)(hx + base + q*8) = z8;
      *(bf16x8*)(lx + base + q*8) = z8;
    }
    return;
  }
  __shared__ u16 zz[32768];   // zh[128t][128d], zl ; fo f32[64][128] aliases
  u16* zh = zz;
  u16* zl = zz + 16384;
  __shared__ float vt[512], lw1c[512], latbs[128];
  if(tid < 128){
    int c = tid >> 5, tc = (tid & 31)*4;
    *(float4*)(vt + c*128 + tc) =
      *(const float4*)(vterm + ((long)b*4 + c)*T_ + t0 + tc);
  } else {
    int i = (tid - 128)*4;
    *(float4*)(lw1c + i) = *(const float4*)(lw1 + i);
  }
  if(tid < 32)
    *(float4*)(latbs + tid*4) = *(const float4*)(latb + b*128 + tid*4);
  __syncthreads();
  { // z1[t][d] = silu(latb + sum_c lw1[c][d] v[c][t]) -> split -> LDS
    int t = tid >> 1, dh = (tid & 1)*64;
    float v0 = vt[t], v1 = vt[128+t], v2 = vt[256+t], v3 = vt[384+t];
    int swz = (t & 7) << 4;
    #pragma unroll
    for(int q=0;q<16;q++){
      int d0 = dh + q*4;
      float4 w0 = *(const float4*)(lw1c + d0);
      float4 w1 = *(const float4*)(lw1c + 128 + d0);
      float4 w2 = *(const float4*)(lw1c + 256 + d0);
      float4 w3 = *(const float4*)(lw1c + 384 + d0);
      float4 lb = *(const float4*)(latbs + d0);
      u16 h0,h1,h2,h3,l0,l1,l2,l3;
      silu_split(lb.x + w0.x*v0 + w1.x*v1 + w2.x*v2 + w3.x*v3, h0, l0);
      silu_split(lb.y + w0.y*v0 + w1.y*v1 + w2.y*v2 + w3.y*v3, h1, l1);
      silu_split(lb.z + w0.z*v0 + w1.z*v1 + w2.z*v2 + w3.z*v3, h2, l2);
      silu_split(lb.w + w0.w*v0 + w1.w*v1 + w2.w*v2 + w3.w*v3, h3, l3);
      int byt = (t*256 + d0*2) ^ swz;
      uint2 hv = make_uint2((unsigned)h0 | ((unsigned)h1<<16),
                            (unsigned)h2 | ((unsigned)h3<<16));
      uint2 lv = make_uint2((unsigned)l0 | ((unsigned)l1<<16),
                            (unsigned)l2 | ((unsigned)l3<<16));
      *(uint2*)((char*)zh + byt) = hv;
      *(uint2*)((char*)zl + byt) = lv;
    }
  }
  __syncthreads();
  int lane = tid & 63, w = tid >> 6;
  int l15 = lane & 15, lhi = lane >> 4;
  int n0 = w*32;
  f32x4 acc[4][2];
  #pragma unroll
  for(int mi=0;mi<4;mi++){
    #pragma unroll
    for(int ni=0;ni<2;ni++) acc[mi][ni] = (f32x4){0.f,0.f,0.f,0.f};
  }
  #pragma unroll
  for(int ks=0; ks<4; ++ks){
    bf16x8 Ah[4], Al[4], Bh[2], Bl[2];
    #pragma unroll
    for(int mi=0;mi<4;mi++){
      int o = mi*16 + l15;
      long off = (long)o*128 + ks*32 + lhi*8;
      Ah[mi] = *(const bf16x8*)(lw2Th + off);
      Al[mi] = *(const bf16x8*)(lw2Tl + off);
    }
    #pragma unroll
    for(int ni=0;ni<2;ni++){
      int t = n0 + ni*16 + l15;
      int byt = (t*256 + (ks*32 + lhi*8)*2) ^ ((t & 7) << 4);
      Bh[ni] = *(bf16x8*)((char*)zh + byt);
      Bl[ni] = *(bf16x8*)((char*)zl + byt);
    }
    #pragma unroll
    for(int mi=0;mi<4;mi++){
      #pragma unroll
      for(int ni=0;ni<2;ni++){
        acc[mi][ni] = mfma16(Ah[mi], Bh[ni], acc[mi][ni]);
        acc[mi][ni] = mfma16(Al[mi], Bh[ni], acc[mi][ni]);
        acc[mi][ni] = mfma16(Ah[mi], Bl[ni], acc[mi][ni]);
      }
    }
  }
  __syncthreads();
  float* fo = (float*)zz;   // [64 o][128 t], xor-swizzled
  #pragma unroll
  for(int mi=0;mi<4;mi++){
    #pragma unroll
    for(int ni=0;ni<2;ni++){
      #pragma unroll
      for(int r=0;r<4;r++){
        int o = mi*16 + lhi*4 + r;
        int tl = n0 + ni*16 + l15;
        fo[o*128 + (tl ^ ((o&7)<<2))] = acc[mi][ni][r];
      }
    }
  }
  __syncthreads();
  #pragma unroll
  for(int q=0;q<8;q++){
    int idx = q*256 + tid;
    int o = idx >> 5, tb = idx & 31;
    float4 rd = *(const float4*)(fo + o*128 + ((tb*4) ^ ((o&7)<<2)));
    float bias = lb2[o];
    u16 h0,h1,h2,h3,l0,l1,l2,l3;
    silu_split(rd.x + bias, h0, l0);
    silu_split(rd.y + bias, h1, l1);
    silu_split(rd.z + bias, h2, l2);
    silu_split(rd.w + bias, h3, l3);
    long base = ((long)b*64 + o)*TPAD_ + t0 + tb*4;
    *(uint2*)(hx + base) = make_uint2((unsigned)h0 | ((unsigned)h1<<16),
                                      (unsigned)h2 | ((unsigned)h3<<16));
    *(uint2*)(lx + base) = make_uint2((unsigned)l0 | ((unsigned)l1<<16),
                                      (unsigned)l2 | ((unsigned)l3<<16));
  }
}

// ---------------------------------------------------------------- forward DFT (pure MFMA, no LDS)
// xfp[s][(b*64+c)][j] = sum_{t in split s} h[b][c][t] * F[t][j]
__global__ __launch_bounds__(256) void k_dft(
    const u16* __restrict__ hx, const u16* __restrict__ lx,
    const u16* __restrict__ invFh, const u16* __restrict__ invFl,
    float* __restrict__ xfp)
{
  int b = blockIdx.x, s = blockIdx.y, tid = threadIdx.x;
  int lane = tid & 63, w = tid >> 6;
  int l15 = lane & 15, lhi = lane >> 4;
  long k0 = (long)s*768;
  const u16* rowAh = hx + ((long)b*64 + w*16 + l15)*TPAD_ + k0 + lhi*8;
  const u16* rowAl = lx + ((long)b*64 + w*16 + l15)*TPAD_ + k0 + lhi*8;
  const u16* rowBh = invFh + (long)l15*TPAD_ + k0 + lhi*8;
  const u16* rowBl = invFl + (long)l15*TPAD_ + k0 + lhi*8;
  f32x4 acc[8];
  #pragma unroll
  for(int ni=0;ni<8;ni++) acc[ni] = (f32x4){0.f,0.f,0.f,0.f};
  #pragma unroll 2
  for(int ks=0; ks<24; ++ks){
    bf16x8 Ah = *(const bf16x8*)(rowAh + ks*32);
    bf16x8 Al = *(const bf16x8*)(rowAl + ks*32);
    #pragma unroll
    for(int ni=0;ni<8;ni++){
      bf16x8 Bh = *(const bf16x8*)(rowBh + (long)ni*16*TPAD_ + ks*32);
      bf16x8 Bl = *(const bf16x8*)(rowBl + (long)ni*16*TPAD_ + ks*32);
      acc[ni] = mfma16(Ah, Bh, acc[ni]);
      acc[ni] = mfma16(Al, Bh, acc[ni]);
      acc[ni] = mfma16(Ah, Bl, acc[ni]);
    }
  }
  #pragma unroll
  for(int ni=0;ni<8;ni++){
    #pragma unroll
    for(int r=0;r<4;r++){
      int row = w*16 + lhi*4 + r;
      xfp[((long)s*8192 + b*64 + row)*128 + ni*16 + l15] = acc[ni][r];
    }
  }
}

// ---------------------------------------------------------------- spectral mix
__global__ __launch_bounds__(512) void k_spectral(
    const float* __restrict__ xfp, const float* __restrict__ wr_,
    const float* __restrict__ wi_, u16* __restrict__ coefh,
    u16* __restrict__ coefl, int l)
{
  int b = blockIdx.x, mh = blockIdx.y, tid = threadIdx.x;
  const float* wr = wr_ + (long)l*262144;
  const float* wi = wi_ + (long)l*262144;
  __shared__ float xr[64*36], xi[64*36];
  {
    int c = tid >> 3, mm0 = (tid & 7)*4;
    long base = ((long)(b*64 + c))*128 + mh*32 + mm0;
    float4 sr = make_float4(0.f,0.f,0.f,0.f), si = sr;
    #pragma unroll
    for(int s2=0;s2<KSPLIT;s2++){
      const float* p = xfp + (long)s2*1048576 + base;
      float4 a = *(const float4*)(p);
      float4 d = *(const float4*)(p + 64);
      sr.x += a.x; sr.y += a.y; sr.z += a.z; sr.w += a.w;
      si.x += d.x; si.y += d.y; si.z += d.z; si.w += d.w;
    }
    *(float4*)(xr + c*36 + mm0) = sr;
    *(float4*)(xi + c*36 + mm0) = si;
  }
  __syncthreads();
  int tx = tid & 15, ty = tid >> 4;
  float ar[2][2] = {{0.f,0.f},{0.f,0.f}};
  float ai[2][2] = {{0.f,0.f},{0.f,0.f}};
  #pragma unroll 2
  for(int c=0;c<64;c++){
    float x0r = xr[c*36 + 2*tx], x1r = xr[c*36 + 2*tx + 1];
    float x0i = xi[c*36 + 2*tx], x1i = xi[c*36 + 2*tx + 1];
    #pragma unroll
    for(int oi=0;oi<2;oi++){
      int o = 2*ty + oi;
      long wofs = ((long)(c*64 + o))*64 + mh*32 + 2*tx;
      float2 wrv = *(const float2*)(wr + wofs);
      float2 wiv = *(const float2*)(wi + wofs);
      ar[oi][0] += x0r*wrv.x - x0i*wiv.x;
      ai[oi][0] += x0r*wiv.x + x0i*wrv.x;
      ar[oi][1] += x1r*wrv.y - x1i*wiv.y;
      ai[oi][1] += x1r*wiv.y + x1i*wrv.y;
    }
  }
  #pragma unroll
  for(int j=0;j<2;j++){
    int m = mh*32 + 2*tx + j;
    float sc = (m==0) ? (1.0f/(float)TP_) : (2.0f/(float)TP_);
    #pragma unroll
    for(int oi=0;oi<2;oi++){
      int o = 2*ty + oi;
      long base = ((long)b*64 + o)*128;
      u16 h, l2;
      bf16_split(sc*ar[oi][j], h, l2);
      coefh[base + m] = h; coefl[base + m] = l2;
      bf16_split(sc*ai[oi][j], h, l2);
      coefh[base + 64 + m] = h; coefl[base + 64 + m] = l2;
    }
  }
}

// ---------------------------------------------------------------- inverse DFT + skip (MFMA, in place)
// out[o][t] = sum_k coef[b][o][k] F[t][k] + sum_c skw[o][c] h[c][t] + skb[o]
// last=0: store split(silu(out)); last=1: store split(out). Zero t>=Tp.
__global__ __launch_bounds__(256) void k_idft(
    u16* __restrict__ hx, u16* __restrict__ lx,
    const u16* __restrict__ coefh, const u16* __restrict__ coefl,
    const u16* __restrict__ fwdFh, const u16* __restrict__ fwdFl,
    const u16* __restrict__ skwh, const u16* __restrict__ skwl,
    const float* __restrict__ sb_, int lay, int last)
{
  int tt = blockIdx.x, b = blockIdx.y, tid = threadIdx.x;
  int t0 = tt*128;
  int lane = tid & 63, w = tid >> 6;
  int l15 = lane & 15, lhi = lane >> 4;
  int n0 = w*32;
  __shared__ u16 sh_[16384];           // hh[128t][64c], hl ; fo f32 aliases
  u16* hh = sh_;
  u16* hl = sh_ + 8192;
  { // stage h (already silu'd+split) transposed [t][c]
    int c0 = (tid & 31)*2, tg = tid >> 5;
    const u16* ph0 = hx + ((long)b*64 + c0)*TPAD_ + t0 + tg*16;
    const u16* ph1 = ph0 + TPAD_;
    const u16* pl0 = lx + ((long)b*64 + c0)*TPAD_ + t0 + tg*16;
    const u16* pl1 = pl0 + TPAD_;
    bf16x8 h0a = *(const bf16x8*)(ph0),     h0b = *(const bf16x8*)(ph0 + 8);
    bf16x8 h1a = *(const bf16x8*)(ph1),     h1b = *(const bf16x8*)(ph1 + 8);
    bf16x8 l0a = *(const bf16x8*)(pl0),     l0b = *(const bf16x8*)(pl0 + 8);
    bf16x8 l1a = *(const bf16x8*)(pl1),     l1b = *(const bf16x8*)(pl1 + 8);
    #pragma unroll
    for(int i=0;i<8;i++){
      int t = tg*16 + i;
      int byt = (t*128 + c0*2) ^ ((t & 7) << 4);
      *(unsigned*)((char*)hh + byt) =
        (unsigned)(u16)h0a[i] | ((unsigned)(u16)h1a[i] << 16);
      *(unsigned*)((char*)hl + byt) =
        (unsigned)(u16)l0a[i] | ((unsigned)(u16)l1a[i] << 16);
    }
    #pragma unroll
    for(int i=0;i<8;i++){
      int t = tg*16 + 8 + i;
      int byt = (t*128 + c0*2) ^ ((t & 7) << 4);
      *(unsigned*)((char*)hh + byt) =
        (unsigned)(u16)h0b[i] | ((unsigned)(u16)h1b[i] << 16);
      *(unsigned*)((char*)hl + byt) =
        (unsigned)(u16)l0b[i] | ((unsigned)(u16)l1b[i] << 16);
    }
  }
  f32x4 acc[4][2];
  #pragma unroll
  for(int mi=0;mi<4;mi++){
    #pragma unroll
    for(int ni=0;ni<2;ni++) acc[mi][ni] = (f32x4){0.f,0.f,0.f,0.f};
  }
  // phase 1: spectral, K=128 (coef x trig), global frags
  #pragma unroll
  for(int ks=0; ks<4; ++ks){
    bf16x8 Ah[4], Al[4], Bh[2], Bl[2];
    #pragma unroll
    for(int mi=0;mi<4;mi++){
      int o = mi*16 + l15;
      long off = ((long)(b*64 + o))*128 + ks*32 + lhi*8;
      Ah[mi] = *(const bf16x8*)(coefh + off);
      Al[mi] = *(const bf16x8*)(coefl + off);
    }
    #pragma unroll
    for(int ni=0;ni<2;ni++){
      int t = t0 + n0 + ni*16 + l15;
      long off = (long)t*128 + ks*32 + lhi*8;
      Bh[ni] = *(const bf16x8*)(fwdFh + off);
      Bl[ni] = *(const bf16x8*)(fwdFl + off);
    }
    #pragma unroll
    for(int mi=0;mi<4;mi++){
      #pragma unroll
      for(int ni=0;ni<2;ni++){
        acc[mi][ni] = mfma16(Ah[mi], Bh[ni], acc[mi][ni]);
        acc[mi][ni] = mfma16(Al[mi], Bh[ni], acc[mi][ni]);
        acc[mi][ni] = mfma16(Ah[mi], Bl[ni], acc[mi][ni]);
      }
    }
  }
  __syncthreads();
  // phase 2: skip GEMM, K=64 (skw x h), B from LDS
  #pragma unroll
  for(int ks=0; ks<2; ++ks){
    bf16x8 Ah[4], Al[4], Bh[2], Bl[2];
    #pragma unroll
    for(int mi=0;mi<4;mi++){
      int o = mi*16 + l15;
      long off = (long)lay*4096 + o*64 + ks*32 + lhi*8;
      Ah[mi] = *(const bf16x8*)(skwh + off);
      Al[mi] = *(const bf16x8*)(skwl + off);
    }
    #pragma unroll
    for(int ni=0;ni<2;ni++){
      int t = n0 + ni*16 + l15;
      int byt = (t*128 + (ks*32 + lhi*8)*2) ^ ((t & 7) << 4);
      Bh[ni] = *(bf16x8*)((char*)hh + byt);
      Bl[ni] = *(bf16x8*)((char*)hl + byt);
    }
    #pragma unroll
    for(int mi=0;mi<4;mi++){
      #pragma unroll
      for(int ni=0;ni<2;ni++){
        acc[mi][ni] = mfma16(Ah[mi], Bh[ni], acc[mi][ni]);
        acc[mi][ni] = mfma16(Al[mi], Bh[ni], acc[mi][ni]);
        acc[mi][ni] = mfma16(Ah[mi], Bl[ni], acc[mi][ni]);
      }
    }
  }
  __syncthreads();
  float* fo = (float*)sh_;   // [64 o][128 t], xor-swizzled
  #pragma unroll
  for(int mi=0;mi<4;mi++){
    #pragma unroll
    for(int ni=0;ni<2;ni++){
      #pragma unroll
      for(int r=0;r<4;r++){
        int o = mi*16 + lhi*4 + r;
        int tl = n0 + ni*16 + l15;
        fo[o*128 + (tl ^ ((o&7)<<2))] = acc[mi][ni][r];
      }
    }
  }
  __syncthreads();
  #pragma unroll
  for(int q=0;q<8;q++){
    int idx = q*256 + tid;
    int o = idx >> 5, tb = idx & 31;
    float4 rd = *(const float4*)(fo + o*128 + ((tb*4) ^ ((o&7)<<2)));
    float bias = sb_[lay*64 + o];
    float v[4] = {rd.x + bias, rd.y + bias, rd.z + bias, rd.w + bias};
    int tg = t0 + tb*4;
    #pragma unroll
    for(int j=0;j<4;j++){
      if(tg + j >= TP_) v[j] = 0.f;
      else if(!last)    v[j] = silu_f(v[j]);
    }
    u16 h0,h1,h2,h3,l0,l1,l2,l3;
    bf16_split(v[0], h0, l0);
    bf16_split(v[1], h1, l1);
    bf16_split(v[2], h2, l2);
    bf16_split(v[3], h3, l3);
    long base = ((long)b*64 + o)*TPAD_ + t0 + tb*4;
    *(uint2*)(hx + base) = make_uint2((unsigned)h0 | ((unsigned)h1<<16),
                                      (unsigned)h2 | ((unsigned)h3<<16));
    *(uint2*)(lx + base) = make_uint2((unsigned)l0 | ((unsigned)l1<<16),
                                      (unsigned)l2 | ((unsigned)l3<<16));
  }
}

// ---------------------------------------------------------------- projection (fp32 VALU)
__global__ __launch_bounds__(256) void k_proj(
    const u16* __restrict__ hx, const u16* __restrict__ lx,
    const float* __restrict__ pw1, const float* __restrict__ pb1,
    const float* __restrict__ pw2, const float* __restrict__ pb2,
    float* __restrict__ out)
{
  int tt = blockIdx.x, b = blockIdx.y, tid = threadIdx.x;
  int t0 = tt*128;
  __shared__ float w1s[64*128];
  __shared__ float xt[64*132];
  __shared__ float red[16*132];
  #pragma unroll
  for(int q=0;q<8;q++){
    int idx = q*1024 + tid*4;
    *(float4*)(w1s + idx) = *(const float4*)(pw1 + idx);
  }
  {
    int w = tid >> 2, tq = tid & 3;
    const u16* hrow = hx + ((long)b*64 + w)*TPAD_ + t0;
    const u16* lrow = lx + ((long)b*64 + w)*TPAD_ + t0;
    #pragma unroll
    for(int q=0;q<4;q++){
      int tl = (tq + q*4)*8;
      bf16x8 hv = *(const bf16x8*)(hrow + tl);
      bf16x8 lv = *(const bf16x8*)(lrow + tl);
      float f[8];
      #pragma unroll
      for(int i=0;i<8;i++)
        f[i] = bf2f((u16)hv[i]) + bf2f((u16)lv[i]);
      *(float4*)(xt + w*132 + tl)     = make_float4(f[0],f[1],f[2],f[3]);
      *(float4*)(xt + w*132 + tl + 4) = make_float4(f[4],f[5],f[6],f[7]);
    }
  }
  __syncthreads();
  int tx = tid & 15, ty = tid >> 4;
  float acc[8][8];
  #pragma unroll
  for(int i=0;i<8;i++){
    #pragma unroll
    for(int j=0;j<8;j++) acc[i][j] = 0.f;
  }
  #pragma unroll 4
  for(int k=0;k<64;k++){
    float4 a0 = *(const float4*)(w1s + k*128 + 8*ty);
    float4 a1 = *(const float4*)(w1s + k*128 + 8*ty + 4);
    float4 b0 = *(const float4*)(xt + k*132 + 8*tx);
    float4 b1 = *(const float4*)(xt + k*132 + 8*tx + 4);
    FMA8x8(acc, a0, a1, b0, b1);
  }
  float part[8];
  #pragma unroll
  for(int j=0;j<8;j++) part[j] = 0.f;
  #pragma unroll
  for(int i=0;i<8;i++){
    int d = 8*ty + i;
    float bb = pb1[d], w2v = pw2[d];
    #pragma unroll
    for(int j=0;j<8;j++) part[j] += w2v * silu_f(acc[i][j] + bb);
  }
  *(float4*)(red + ty*132 + 8*tx)     = make_float4(part[0],part[1],part[2],part[3]);
  *(float4*)(red + ty*132 + 8*tx + 4) = make_float4(part[4],part[5],part[6],part[7]);
  __syncthreads();
  if(tid < 128){
    float ssum = pb2[0];
    #pragma unroll
    for(int y=0;y<16;y++) ssum += red[y*132 + tid];
    out[(long)b*T_ + t0 + tid] = ssum;
  }
}

// ---------------------------------------------------------------- launch
extern "C" void kernel_launch(void* const* d_in, const int* in_sizes, int n_in,
                              void* d_out, int out_size, void* d_ws, size_t ws_size,
                              hipStream_t stream)
{
  const float* vterm = (const float*)d_in[0];
  const float* pp    = (const float*)d_in[1];
  const float* ew1   = (const float*)d_in[2];
  const float* eb1   = (const float*)d_in[3];
  const float* ew2   = (const float*)d_in[4];
  const float* eb2   = (const float*)d_in[5];
  const float* ew3   = (const float*)d_in[6];
  const float* eb3   = (const float*)d_in[7];
  const float* lw1   = (const float*)d_in[8];
  const float* lb1   = (const float*)d_in[9];
  const float* lw2   = (const float*)d_in[10];
  const float* lb2   = (const float*)d_in[11];
  const float* swr   = (const float*)d_in[12];
  const float* swi   = (const float*)d_in[13];
  const float* skw   = (const float*)d_in[14];
  const float* skb   = (const float*)d_in[15];
  const float* pw1   = (const float*)d_in[16];
  const float* pb1   = (const float*)d_in[17];
  const float* pw2   = (const float*)d_in[18];
  const float* pb2   = (const float*)d_in[19];
  float* out = (float*)d_out;

  u16* hx     = (u16*)d_ws;
  u16* lxp    = hx + 37748736;
  float* xfp  = (float*)(lxp + 37748736);
  u16* coefh  = (u16*)(xfp + 6291456);
  u16* coefl  = coefh + 1048576;
  u16* fwdFh  = coefl + 1048576;
  u16* fwdFl  = fwdFh + 589824;
  u16* invFh  = fwdFl + 589824;
  u16* invFl  = invFh + 589824;
  u16* skwh   = invFl + 589824;
  u16* skwl   = skwh + 16384;
  float* latb = (float*)coefh;   // dead before spectral writes coef
  u16* lw2Th  = coefl;           // dead before spectral writes coef
  u16* lw2Tl  = coefl + 8192;

  k_tables<<<(TPAD_*64 + 255)/256, 256, 0, stream>>>(fwdFh, fwdFl, invFh, invFl);
  k_prep<<<(NL_*64*64 + 64*128 + 255)/256, 256, 0, stream>>>(
      skw, skwh, skwl, lw2, lw2Th, lw2Tl);
  k_embed<<<B_, 128, 0, stream>>>(pp, ew1, eb1, ew2, eb2, ew3, eb3, lw1, lb1, latb);
  k_lift<<<dim3(TPAD_/128, B_), 256, 0, stream>>>(
      vterm, latb, lw1, lw2Th, lw2Tl, lb2, hx, lxp);
  for(int l=0;l<NL_;l++){
    k_dft<<<dim3(B_, KSPLIT), 256, 0, stream>>>(hx, lxp, invFh, invFl, xfp);
    k_spectral<<<dim3(B_, 2), 512, 0, stream>>>(xfp, swr, swi, coefh, coefl, l);
    k_idft<<<dim3(TPAD_/128, B_), 256, 0, stream>>>(
        hx, lxp, coefh, coefl, fwdFh, fwdFl, skwh, skwl, skb, l, (l==NL_-1) ? 1 : 0);
  }
  k_proj<<<dim3(T_/128, B_), 256, 0, stream>>>(hx, lxp, pw1, pb1, pw2, pb2, out);
}